// Round 8
// baseline (695.368 us; speedup 1.0000x reference)
//
#include <hip/hip_runtime.h>
#include <hip/hip_bf16.h>
#include <cstdint>
#include <cstddef>

// MHA forward. b=4, n=2048, d_model=1024, heads=16, dk=64, causal.
// Inputs: float32 (confirmed R1-R5). Output: float32 (confirmed R5 green).
// Compute: bf16 MFMA, fp32 accumulate; intermediates bf16 row-major [b*n,1024].
//
// R14: GEMM phase still ~260 us after R13's merge (only -18). Diagnosis: the
// k-step is a serial latency chain (~2000 cy vs 80 cy MFMA issue) and 3
// waves/SIMD can't hide it. This round trades per-block MFMA density for
// block-level TLP (the lever behind every win this session):
//   - gemm tile 128x128 -> 64x128 (BM=64): 8 MFMA/step/wave, acc 32 VGPR,
//     LDS 26 KB dbuf; grid (8,128,z) -> QKV = 3072 blocks, 5 blocks/CU
//     (launch_bounds(256,5)); O-proj = 1024 blocks, 4-5/CU (was 2).
//   - flash 4 -> 6 blocks/CU (launch_bounds(256,6); VGPR 64<=85, LDS 144<=160)
//     to fill the 26%-occupancy tail.
// W path unchanged: cvt+swizzle pre-pass, g2l linear [128][32], bv read XOR
// cW = quad*8 ^ ((r16&6)<<2). A reg-staged f32 -> padded [64][40] (2-way).
// Same RNE casts -> bit-identical results. flash algo unchanged (R12).

typedef __bf16 bf16_t;
typedef bf16_t bf16x4 __attribute__((ext_vector_type(4)));
typedef bf16_t bf16x8 __attribute__((ext_vector_type(8)));
typedef float floatx4 __attribute__((ext_vector_type(4)));

#define MFMA(a, b, c) __builtin_amdgcn_mfma_f32_16x16x32_bf16((a), (b), (c), 0, 0, 0)
#define NEG_BIG (-30000.0f)  // exp2-domain sentinel; v_exp_f32 underflows to 0

static __device__ __forceinline__ bf16_t f2bf(float x) { return (bf16_t)x; }

static __device__ __forceinline__ bf16x8 cvt8p(const floatx4 a, const floatx4 b) {
  bf16x8 r;
  r[0] = (bf16_t)a[0]; r[1] = (bf16_t)a[1]; r[2] = (bf16_t)a[2]; r[3] = (bf16_t)a[3];
  r[4] = (bf16_t)b[0]; r[5] = (bf16_t)b[1]; r[6] = (bf16_t)b[2]; r[7] = (bf16_t)b[3];
  return r;
}

// global -> LDS direct copy, 16 B/lane. dest = wave-uniform base + lane*16.
static __device__ __forceinline__ void g2l16(const void* g, void* l) {
  __builtin_amdgcn_global_load_lds(
      (const __attribute__((address_space(1))) void*)g,
      (__attribute__((address_space(3))) void*)l, 16, 0, 0);
}

// f32-vs-bf16 sniffer on w_q's first 64 uint16s (validated: picks f32 path).
__global__ void detect_dtype(const unsigned short* __restrict__ w,
                             int* __restrict__ flag) {
  const unsigned short u = w[threadIdx.x];
  const bool big = (u & 0x7F80u) >= 0x3F80u;
  const unsigned long long m = __ballot(big);
  if (threadIdx.x == 0) *flag = (m != 0ull) ? 1 : 0;
}

// ---------------------------------------------------------------------------
// W cvt + bank-swizzle: dst[r][c] = src[r][c ^ ((r&6)<<2)] (flips col bits 3,4
// within each 32-col block; involution; preserves 8-elem alignment).
// grid (512, nmat); blockIdx.y picks src; dst slots are 1M elems apart.
// ---------------------------------------------------------------------------
__global__ __launch_bounds__(256)
void cvt_w_swz(const void* __restrict__ s0, const void* __restrict__ s1,
               const void* __restrict__ s2, bf16_t* __restrict__ dst,
               const int* __restrict__ flag)
{
  const void* src = blockIdx.y == 0 ? s0 : (blockIdx.y == 1 ? s1 : s2);
  bf16_t* d = dst + (size_t)blockIdx.y * (1024 * 1024);
  const int i    = blockIdx.x * 256 + threadIdx.x;  // 0..131071
  const int row  = i >> 7;
  const int col0 = (i & 127) * 8;
  const int dcol = col0 ^ ((row & 6) << 2);
  bf16x8 v;
  if (*flag) {
    const float* s = (const float*)src + (size_t)row * 1024 + col0;
    v = cvt8p(*(const floatx4*)s, *(const floatx4*)(s + 4));
  } else {
    v = *(const bf16x8*)((const bf16_t*)src + (size_t)row * 1024 + col0);
  }
  *(bf16x8*)(d + (size_t)row * 1024 + dcol) = v;
}

// XCD remap per 8x128 slab (1024 blocks, %8==0 -> bijective):
// XCD j <- f%8 owns 16 bm-panels (64 rows each) x all 8 bn.
static __device__ __forceinline__ void gemm_tile_map(int& bm, int& bn) {
  const int f  = (int)(blockIdx.y * gridDim.x + blockIdx.x);
  const int xj = f & 7, sq = f >> 3;          // sq 0..127
  bm = ((xj << 4) | (sq >> 3)) * 64;          // 128 panels of 64 rows
  bn = (sq & 7) * 128;
}

// ---------------------------------------------------------------------------
// gemm_rs: C[M,1024] = A[M,1024] @ W[1024,1024]^T.  Tile 64x128, BK=32,
// 4 waves (1x4: wave w owns cols [w*32,w*32+32)), 4x2 mfma_16x16x32/wave.
// A reg-staged (f32->cvt or bf16) -> padded [64][40] LDS (2-way = free).
// W bf16 pre-swizzled in global -> linear [128][32] via g2l; bv read applies
// cW = quad*8 ^ ((r16&6)<<2). Double-buffered, ONE barrier per k-step:
// sync(t) drains W g2l(t) (issued after sync(t-1), hidden under compute(t-1));
// A(t) regs loaded after sync(t-1), written to LDS at top of t.
// ---------------------------------------------------------------------------
template <bool AF32, typename OutT>
static __device__ __forceinline__
void gemm_rs_core(const void* __restrict__ Av, const bf16_t* __restrict__ W,
                  OutT* __restrict__ C,
                  bf16_t (*sA)[64 * 40], bf16_t (*sB)[128 * 32])
{
  const int K = 1024;
  const int tid  = threadIdx.x;
  const int wave = tid >> 6;
  const int lane = tid & 63;
  int bm, bn;
  gemm_tile_map(bm, bn);
  const int quad = lane >> 4, r16 = lane & 15;
  const int cW = (quad * 8) ^ ((r16 & 6) << 2);  // swizzled W read col

  floatx4 acc[4][2];
  #pragma unroll
  for (int i = 0; i < 4; ++i)
    #pragma unroll
    for (int j = 0; j < 2; ++j) acc[i][j] = {0.f, 0.f, 0.f, 0.f};

  // A reg-stage geometry: one row per thread (srow 0..63), 8 elems
  const int srow = tid >> 2;
  const int scol = (tid & 3) * 8;
  const size_t a0 = (size_t)(bm + srow) * K + scol;

  // W g2l geometry (chunk = wave*2 + c; 16 rows x 32 cols = 1 KB each)
  const int ch0 = wave * 2;
  const int r0  = lane >> 2;
  const int ce  = (lane & 3) * 8;
  const bf16_t* Wg0 = W + (size_t)(bn + ch0 * 16 + r0) * K + ce;
  const bf16_t* Wg1 = Wg0 + (size_t)16 * K;

  floatx4 fa[2];
  bf16x8  ba;
  auto stageA = [&](int k0) {
    if constexpr (AF32) {
      const float* Af = (const float*)Av;
      fa[0] = *(const floatx4*)(Af + a0 + k0);
      fa[1] = *(const floatx4*)(Af + a0 + k0 + 4);
    } else {
      ba = *(const bf16x8*)((const bf16_t*)Av + a0 + k0);
    }
  };

  stageA(0);
  g2l16(Wg0, &sB[0][ch0 * 512]);
  g2l16(Wg1, &sB[0][(ch0 + 1) * 512]);

  for (int t = 0; t < 32; ++t) {
    const int buf = t & 1;
    {  // A(t) regs -> LDS (WAR-safe: last reader passed sync(t-1))
      bf16x8 va;
      if constexpr (AF32) va = cvt8p(fa[0], fa[1]);
      else                va = ba;
      *(bf16x8*)&sA[buf][srow * 40 + scol] = va;
    }
    __syncthreads();  // drains W g2l(t); A writes visible
    if (t + 1 < 32) {
      const int k0 = (t + 1) * 32;
      g2l16(Wg0 + k0, &sB[buf ^ 1][ch0 * 512]);
      g2l16(Wg1 + k0, &sB[buf ^ 1][(ch0 + 1) * 512]);
      stageA(k0);
    }

    bf16x8 af[4], bv[2];
    #pragma unroll
    for (int mi = 0; mi < 4; ++mi)
      af[mi] = *(const bf16x8*)&sA[buf][(mi * 16 + r16) * 40 + quad * 8];
    #pragma unroll
    for (int ni = 0; ni < 2; ++ni)
      bv[ni] = *(const bf16x8*)&sB[buf][(wave * 32 + ni * 16 + r16) * 32 + cW];
    #pragma unroll
    for (int mi = 0; mi < 4; ++mi)
      #pragma unroll
      for (int ni = 0; ni < 2; ++ni)
        acc[mi][ni] = MFMA(af[mi], bv[ni], acc[mi][ni]);
  }

  #pragma unroll
  for (int mi = 0; mi < 4; ++mi)
    #pragma unroll
    for (int ni = 0; ni < 2; ++ni)
      #pragma unroll
      for (int r = 0; r < 4; ++r) {
        const int row = bm + mi * 16 + quad * 4 + r;
        const int col = bn + wave * 32 + ni * 16 + r16;
        C[(size_t)row * 1024 + col] = (OutT)acc[mi][ni][r];
      }
}

// ADT 0: A external (f32/bf16 per flag), z in {0,1,2} picks A/W/C.
// ADT 1: A internal bf16 (grid z=1).
template <int ADT, typename OutT>
__global__ __launch_bounds__(256, 5)
void gemm_rs(const void* __restrict__ A0, const void* __restrict__ A1,
             const void* __restrict__ A2, const bf16_t* __restrict__ Wb,
             OutT* __restrict__ C0, OutT* __restrict__ C1,
             OutT* __restrict__ C2, const int* __restrict__ flag)
{
  __shared__ __align__(16) bf16_t sA[2][64 * 40];   // 10 KB
  __shared__ __align__(16) bf16_t sB[2][128 * 32];  // 16 KB
  const int z = blockIdx.z;
  const void*   A = z == 0 ? A0 : (z == 1 ? A1 : A2);
  const bf16_t* W = Wb + (size_t)z * (1024 * 1024);
  OutT*         C = z == 0 ? C0 : (z == 1 ? C1 : C2);
  if (ADT == 0 && *flag) gemm_rs_core<true,  OutT>(A, W, C, sA, sB);
  else                   gemm_rs_core<false, OutT>(A, W, C, sA, sB);
}

// ---------------------------------------------------------------------------
// Causal MFMA flash attention over row-major [8192][1024] bf16 q/k/v, head =
// 64-col slice. Block = 256 threads (4 waves): one (bh, 64-row q-tile).
// Wave w owns q-rows [w*16, w*16+16). BKV = 64. Swapped QK^T: lane owns one
// q-row -> lane-local softmax (15 fmax + 2 shfl), T13 skip-rescale, bf16x4 P
// stores. XCD-grouped block map (K/V L2-hot), heavy tiles first. LDS 24 KB
// swizzled (idx = row*64 + (col^((row&7)<<3))). K/V reg-prefetch (T14).
// R14: 6 blocks/CU (was 4) to fill the 26%-occupancy tail.
// ---------------------------------------------------------------------------
__global__ __launch_bounds__(256, 6)
void flash_attn(bf16_t* qio, const bf16_t* __restrict__ kh,
                const bf16_t* __restrict__ vh)
{
  __shared__ __align__(16) bf16_t sK[64 * 64];    // [kv][d]  8 KB, swizzled
  __shared__ __align__(16) bf16_t sVt[64 * 64];   // [d][kv]  8 KB, swizzled
  __shared__ __align__(16) bf16_t sP[64 * 64];    // [q][kv]  8 KB, swizzled
  const int tid  = threadIdx.x;
  const int wave = tid >> 6;
  const int lane = tid & 63;
  const int quad = lane >> 4, r16 = lane & 15;

  const int f  = (int)(blockIdx.y * gridDim.x + blockIdx.x);
  const int xj = f & 7, sq = f >> 3;
  const int bh = xj + (sq >> 5) * 8;
  const int q0 = (31 - (sq & 31)) * 64;
  const int b = bh >> 4, h = bh & 15;
  const size_t hb = ((size_t)b * 2048) * 1024 + (size_t)h * 64;
  const int swl = (r16 & 7) << 3;  // swizzle XOR for r16-indexed rows

  bf16x8 qf[2];
  #pragma unroll
  for (int ks = 0; ks < 2; ++ks)
    qf[ks] = *(const bf16x8*)(qio + hb +
        (size_t)(q0 + wave * 16 + r16) * 1024 + ks * 32 + quad * 8);

  floatx4 o[4];
  #pragma unroll
  for (int nd = 0; nd < 4; ++nd) o[nd] = {0.f, 0.f, 0.f, 0.f};
  float mrow = NEG_BIG, lrow = 0.f;  // state for q-row (wave*16 + r16)

  const float sc = 0.125f * 1.44269504089f;  // 1/sqrt(64) * log2(e)
  const int kend = q0 + 64;
  const int qrow = q0 + wave * 16 + r16;

  bf16x8 kst[2], vst[2];
  #pragma unroll
  for (int j = 0; j < 2; ++j) {
    const int c = j * 256 + tid;
    kst[j] = *(const bf16x8*)(kh + hb + (size_t)(c >> 3) * 1024 + (c & 7) * 8);
    vst[j] = *(const bf16x8*)(vh + hb + (size_t)(c & 63) * 1024 + (c >> 6) * 8);
  }

  for (int kv0 = 0; kv0 < kend; kv0 += 64) {
    #pragma unroll
    for (int j = 0; j < 2; ++j) {
      const int c = j * 256 + tid;
      const int krow = c >> 3, kcol = (c & 7) * 8;
      *(bf16x8*)&sK[krow * 64 + (kcol ^ ((krow & 7) << 3))] = kst[j];
      const int vkv = c & 63, vd = (c >> 6) * 8;
      #pragma unroll
      for (int e = 0; e < 8; ++e)        // row = vd+e, (row&7)==e since vd%8==0
        sVt[(vd + e) * 64 + (vkv ^ (e << 3))] = vst[j][e];
    }
    __syncthreads();

    if (kv0 + 64 < kend) {
      #pragma unroll
      for (int j = 0; j < 2; ++j) {
        const int c = j * 256 + tid;
        kst[j] = *(const bf16x8*)(kh + hb + (size_t)(kv0 + 64 + (c >> 3)) * 1024 + (c & 7) * 8);
        vst[j] = *(const bf16x8*)(vh + hb + (size_t)(kv0 + 64 + (c & 63)) * 1024 + (c >> 6) * 8);
      }
    }

    floatx4 st[4];
    #pragma unroll
    for (int nk = 0; nk < 4; ++nk) st[nk] = {0.f, 0.f, 0.f, 0.f};
    #pragma unroll
    for (int ks = 0; ks < 2; ++ks) {
      bf16x8 bk[4];
      #pragma unroll
      for (int nk = 0; nk < 4; ++nk)
        bk[nk] = *(const bf16x8*)&sK[(nk * 16 + r16) * 64 + ((ks * 32 + quad * 8) ^ swl)];
      #pragma unroll
      for (int nk = 0; nk < 4; ++nk)
        st[nk] = MFMA(bk[nk], qf[ks], st[nk]);  // swapped operands
    }

    const bool domask = (kv0 + 63 > q0 + wave * 16);  // wave-uniform
    #pragma unroll
    for (int nk = 0; nk < 4; ++nk)
      #pragma unroll
      for (int r = 0; r < 4; ++r) {
        float t = st[nk][r] * sc;
        if (domask && (kv0 + nk * 16 + quad * 4 + r > qrow)) t = NEG_BIG;
        st[nk][r] = t;
      }

    float mx = fmaxf(fmaxf(st[0][0], st[0][1]), fmaxf(st[0][2], st[0][3]));
    #pragma unroll
    for (int nk = 1; nk < 4; ++nk)
      mx = fmaxf(mx, fmaxf(fmaxf(st[nk][0], st[nk][1]),
                           fmaxf(st[nk][2], st[nk][3])));
    mx = fmaxf(mx, __shfl_xor(mx, 16, 64));
    mx = fmaxf(mx, __shfl_xor(mx, 32, 64));

    if (!__all(mx <= mrow)) {            // T13: skip rescale if no max grew
      const float mnew  = fmaxf(mrow, mx);
      const float alpha = exp2f(mrow - mnew);
      mrow = mnew;
      lrow *= alpha;
      #pragma unroll
      for (int r = 0; r < 4; ++r) {
        const float ar = __shfl(alpha, quad * 4 + r, 64);
        #pragma unroll
        for (int nd = 0; nd < 4; ++nd) o[nd][r] *= ar;
      }
    }

    float ls = 0.f;
    #pragma unroll
    for (int nk = 0; nk < 4; ++nk) {
      bf16x4 pk;
      #pragma unroll
      for (int r = 0; r < 4; ++r) {
        const bf16_t pb = f2bf(exp2f(st[nk][r] - mrow));
        ls += (float)pb;  // denominator matches the bf16 P used in PV
        pk[r] = pb;
      }
      *(bf16x4*)&sP[(wave * 16 + r16) * 64 + ((nk * 16 + quad * 4) ^ swl)] = pk;
    }
    ls += __shfl_xor(ls, 16, 64);
    ls += __shfl_xor(ls, 32, 64);
    lrow += ls;
    __syncthreads();  // sP visible across lanes

    #pragma unroll
    for (int ks = 0; ks < 2; ++ks) {
      const int cb = (ks * 32 + quad * 8) ^ swl;
      const bf16x8 pa = *(const bf16x8*)&sP[(wave * 16 + r16) * 64 + cb];
      bf16x8 vb[4];
      #pragma unroll
      for (int nd = 0; nd < 4; ++nd)
        vb[nd] = *(const bf16x8*)&sVt[(nd * 16 + r16) * 64 + cb];
      #pragma unroll
      for (int nd = 0; nd < 4; ++nd)
        o[nd] = MFMA(pa, vb[nd], o[nd]);
    }
    __syncthreads();  // protect sK/sVt/sP for next iteration
  }

  #pragma unroll
  for (int r = 0; r < 4; ++r) {
    const float lr  = __shfl(lrow, quad * 4 + r, 64);
    const float inv = 1.f / lr;
    const int row = q0 + wave * 16 + quad * 4 + r;
    #pragma unroll
    for (int nd = 0; nd < 4; ++nd)
      qio[hb + (size_t)row * 1024 + nd * 16 + r16] = f2bf(o[nd][r] * inv);
  }
}

// ---------------------------------------------------------------------------
extern "C" void kernel_launch(void* const* d_in, const int* in_sizes, int n_in,
                              void* d_out, int out_size, void* d_ws, size_t ws_size,
                              hipStream_t stream) {
  (void)in_sizes; (void)n_in; (void)out_size; (void)ws_size;
  const size_t TSZ = (size_t)8192 * 1024;       // elems per [8192,1024] bf16
  int*    flag = (int*)d_ws;
  bf16_t* qws  = (bf16_t*)((char*)d_ws + 16);   // ws lo  16 MB
  bf16_t* kws  = qws + TSZ;                     // ws hi  16 MB (W_o slot later)
  bf16_t* vws  = (bf16_t*)d_out;                // d_out lo 16 MB (bf16 V)
  bf16_t* wsl  = (bf16_t*)d_out + TSZ;          // d_out hi: 3 x 2 MB W slots

  detect_dtype<<<1, 64, 0, stream>>>((const unsigned short*)d_in[3], flag);

  // convert+swizzle w_q, w_k, w_v into the three slots
  cvt_w_swz<<<dim3(512, 3), 256, 0, stream>>>(d_in[3], d_in[4], d_in[5], wsl, flag);

  // fused Q/K/V projections: one dispatch, 3072 blocks (5 blocks/CU)
  gemm_rs<0, bf16_t><<<dim3(8, 128, 3), 256, 0, stream>>>(
      d_in[0], d_in[1], d_in[2], wsl, qws, kws, vws, flag);

  flash_attn<<<dim3(64, 32), 256, 0, stream>>>(qws, kws, vws);

  // K dead -> its ws region holds converted+swizzled w_o
  cvt_w_swz<<<dim3(512, 1), 256, 0, stream>>>(d_in[6], d_in[6], d_in[6], kws, flag);

  // output projection: A = qws (bf16, internal), C = f32 d_out (full 32 MB)
  gemm_rs<1, float><<<dim3(8, 128, 1), 256, 0, stream>>>(
      qws, qws, qws, kws, (float*)d_out, (float*)d_out, (float*)d_out, flag);
}

// Round 9
// 396.095 us; speedup vs baseline: 1.7556x; 1.7556x over previous
//
#include <hip/hip_runtime.h>
#include <hip/hip_bf16.h>
#include <cstdint>
#include <cstddef>

// MHA forward. b=4, n=2048, d_model=1024, heads=16, dk=64, causal.
// Inputs: float32 (confirmed R1-R5). Output: float32 (confirmed R5 green).
// Compute: bf16 MFMA, fp32 accumulate; intermediates bf16 row-major [b*n,1024].
//
// R15: R14's launch_bounds(256,6) on flash forced VGPR 64->40 -> spills ->
// 1.1 GB HBM scratch traffic per dispatch (FETCH 732 MB), 143->429 us.
// R14's BM=64 GEMM was neutral (phase 266 vs 259) - second dead TLP theory.
//   - flash: exact R12 revert (launch_bounds(256,4), VGPR 64, no spill).
//   - QKV: exact R13 (128x128, 3 blocks/CU, pre-swizzled W via g2l).
//   - O-proj ONLY: retiled 64x128 -> 1024 blocks (was 512 = 2/CU, the worst
//     TLP in the pipeline), launch_bounds(256,4). A internal bf16 (no f32
//     staging regs). Isolated change -> clean attribution from total delta.

typedef __bf16 bf16_t;
typedef bf16_t bf16x4 __attribute__((ext_vector_type(4)));
typedef bf16_t bf16x8 __attribute__((ext_vector_type(8)));
typedef float floatx4 __attribute__((ext_vector_type(4)));

#define MFMA(a, b, c) __builtin_amdgcn_mfma_f32_16x16x32_bf16((a), (b), (c), 0, 0, 0)
#define NEG_BIG (-30000.0f)  // exp2-domain sentinel; v_exp_f32 underflows to 0

static __device__ __forceinline__ bf16_t f2bf(float x) { return (bf16_t)x; }

static __device__ __forceinline__ bf16x8 cvt8p(const floatx4 a, const floatx4 b) {
  bf16x8 r;
  r[0] = (bf16_t)a[0]; r[1] = (bf16_t)a[1]; r[2] = (bf16_t)a[2]; r[3] = (bf16_t)a[3];
  r[4] = (bf16_t)b[0]; r[5] = (bf16_t)b[1]; r[6] = (bf16_t)b[2]; r[7] = (bf16_t)b[3];
  return r;
}

// global -> LDS direct copy, 16 B/lane. dest = wave-uniform base + lane*16.
static __device__ __forceinline__ void g2l16(const void* g, void* l) {
  __builtin_amdgcn_global_load_lds(
      (const __attribute__((address_space(1))) void*)g,
      (__attribute__((address_space(3))) void*)l, 16, 0, 0);
}

// f32-vs-bf16 sniffer on w_q's first 64 uint16s (validated: picks f32 path).
__global__ void detect_dtype(const unsigned short* __restrict__ w,
                             int* __restrict__ flag) {
  const unsigned short u = w[threadIdx.x];
  const bool big = (u & 0x7F80u) >= 0x3F80u;
  const unsigned long long m = __ballot(big);
  if (threadIdx.x == 0) *flag = (m != 0ull) ? 1 : 0;
}

// ---------------------------------------------------------------------------
// W cvt + bank-swizzle: dst[r][c] = src[r][c ^ ((r&6)<<2)] (flips col bits 3,4
// within each 32-col block; involution; preserves 8-elem alignment).
// grid (512, nmat); blockIdx.y picks src; dst slots are 1M elems apart.
// ---------------------------------------------------------------------------
__global__ __launch_bounds__(256)
void cvt_w_swz(const void* __restrict__ s0, const void* __restrict__ s1,
               const void* __restrict__ s2, bf16_t* __restrict__ dst,
               const int* __restrict__ flag)
{
  const void* src = blockIdx.y == 0 ? s0 : (blockIdx.y == 1 ? s1 : s2);
  bf16_t* d = dst + (size_t)blockIdx.y * (1024 * 1024);
  const int i    = blockIdx.x * 256 + threadIdx.x;  // 0..131071
  const int row  = i >> 7;
  const int col0 = (i & 127) * 8;
  const int dcol = col0 ^ ((row & 6) << 2);
  bf16x8 v;
  if (*flag) {
    const float* s = (const float*)src + (size_t)row * 1024 + col0;
    v = cvt8p(*(const floatx4*)s, *(const floatx4*)(s + 4));
  } else {
    v = *(const bf16x8*)((const bf16_t*)src + (size_t)row * 1024 + col0);
  }
  *(bf16x8*)(d + (size_t)row * 1024 + dcol) = v;
}

// XCD remap, 512-block slab (8x64): XCD j <- f%8 owns 8 bm-panels (128 rows)
// x all 8 bn. Bijective (512 % 8 == 0). A/W panels L2-hot.
static __device__ __forceinline__ void gemm_tile_map(int& bm, int& bn) {
  const int f  = (int)(blockIdx.y * gridDim.x + blockIdx.x);
  const int xj = f & 7, sq = f >> 3;
  bm = ((xj << 3) | (sq >> 3)) * 128;
  bn = (sq & 7) * 128;
}

// XCD remap, 1024-block slab (8x128): XCD j owns 16 bm-panels (64 rows) x 8 bn.
static __device__ __forceinline__ void gemm_tile_map64(int& bm, int& bn) {
  const int f  = (int)(blockIdx.y * gridDim.x + blockIdx.x);
  const int xj = f & 7, sq = f >> 3;          // sq 0..127
  bm = ((xj << 4) | (sq >> 3)) * 64;
  bn = (sq & 7) * 128;
}

// ---------------------------------------------------------------------------
// gemm_rs (QKV): C[M,1024] = A[M,1024] @ W[1024,1024]^T. Tile 128x128, BK=32,
// 4 waves (2x2), 4x4 mfma_16x16x32/wave. A reg-staged (f32->cvt or bf16) ->
// padded [128][40] LDS (2-way = free). W bf16 pre-swizzled in global ->
// linear [128][32] via g2l; bv read applies cW = quad*8 ^ ((r16&6)<<2).
// Double-buffered, ONE barrier per k-step.                       [R13 exact]
// ---------------------------------------------------------------------------
template <bool AF32, typename OutT>
static __device__ __forceinline__
void gemm_rs_core(const void* __restrict__ Av, const bf16_t* __restrict__ W,
                  OutT* __restrict__ C,
                  bf16_t (*sA)[128 * 40], bf16_t (*sB)[128 * 32])
{
  const int K = 1024;
  const int tid  = threadIdx.x;
  const int wave = tid >> 6;
  const int lane = tid & 63;
  const int wm = wave >> 1, wn = wave & 1;
  int bm, bn;
  gemm_tile_map(bm, bn);
  const int quad = lane >> 4, r16 = lane & 15;
  const int cW = (quad * 8) ^ ((r16 & 6) << 2);  // swizzled W read col

  floatx4 acc[4][4];
  #pragma unroll
  for (int i = 0; i < 4; ++i)
    #pragma unroll
    for (int j = 0; j < 4; ++j) acc[i][j] = {0.f, 0.f, 0.f, 0.f};

  // A reg-stage geometry (rows bm+srow, bm+srow+64; 8 elems each)
  const int srow = tid >> 2;
  const int scol = (tid & 3) * 8;
  const size_t a0 = (size_t)(bm + srow) * K + scol;
  const size_t a1 = a0 + (size_t)64 * K;

  // W g2l geometry (chunk = wave*2 + c; 16 rows x 32 cols = 1 KB each)
  const int ch0 = wave * 2;
  const int r0  = lane >> 2;
  const int ce  = (lane & 3) * 8;
  const bf16_t* Wg0 = W + (size_t)(bn + ch0 * 16 + r0) * K + ce;
  const bf16_t* Wg1 = Wg0 + (size_t)16 * K;

  floatx4 fa[2][2];
  bf16x8  ba[2];
  auto stageA = [&](int k0) {
    if constexpr (AF32) {
      const float* Af = (const float*)Av;
      fa[0][0] = *(const floatx4*)(Af + a0 + k0);
      fa[0][1] = *(const floatx4*)(Af + a0 + k0 + 4);
      fa[1][0] = *(const floatx4*)(Af + a1 + k0);
      fa[1][1] = *(const floatx4*)(Af + a1 + k0 + 4);
    } else {
      const bf16_t* Ab = (const bf16_t*)Av;
      ba[0] = *(const bf16x8*)(Ab + a0 + k0);
      ba[1] = *(const bf16x8*)(Ab + a1 + k0);
    }
  };

  stageA(0);
  g2l16(Wg0, &sB[0][ch0 * 512]);
  g2l16(Wg1, &sB[0][(ch0 + 1) * 512]);

  for (int t = 0; t < 32; ++t) {
    const int buf = t & 1;
    {  // A(t) regs -> LDS (WAR-safe: last reader passed sync(t-1))
      bf16x8 va0, va1;
      if constexpr (AF32) { va0 = cvt8p(fa[0][0], fa[0][1]); va1 = cvt8p(fa[1][0], fa[1][1]); }
      else                { va0 = ba[0]; va1 = ba[1]; }
      *(bf16x8*)&sA[buf][srow * 40 + scol]        = va0;
      *(bf16x8*)&sA[buf][(srow + 64) * 40 + scol] = va1;
    }
    __syncthreads();  // drains W g2l(t); A writes visible
    if (t + 1 < 32) {
      const int k0 = (t + 1) * 32;
      g2l16(Wg0 + k0, &sB[buf ^ 1][ch0 * 512]);
      g2l16(Wg1 + k0, &sB[buf ^ 1][(ch0 + 1) * 512]);
      stageA(k0);
    }

    bf16x8 af[4], bv[4];
    #pragma unroll
    for (int mi = 0; mi < 4; ++mi)
      af[mi] = *(const bf16x8*)&sA[buf][(wm * 64 + mi * 16 + r16) * 40 + quad * 8];
    #pragma unroll
    for (int ni = 0; ni < 4; ++ni)
      bv[ni] = *(const bf16x8*)&sB[buf][(wn * 64 + ni * 16 + r16) * 32 + cW];
    #pragma unroll
    for (int mi = 0; mi < 4; ++mi)
      #pragma unroll
      for (int ni = 0; ni < 4; ++ni)
        acc[mi][ni] = MFMA(af[mi], bv[ni], acc[mi][ni]);
  }

  #pragma unroll
  for (int mi = 0; mi < 4; ++mi)
    #pragma unroll
    for (int ni = 0; ni < 4; ++ni)
      #pragma unroll
      for (int r = 0; r < 4; ++r) {
        const int row = bm + wm * 64 + mi * 16 + quad * 4 + r;
        const int col = bn + wn * 64 + ni * 16 + r16;
        C[(size_t)row * 1024 + col] = (OutT)acc[mi][ni][r];
      }
}

template <typename OutT>
__global__ __launch_bounds__(256, 3)
void gemm_rs(const void* __restrict__ A0, const void* __restrict__ A1,
             const void* __restrict__ A2, const bf16_t* __restrict__ Wb,
             OutT* __restrict__ C0, OutT* __restrict__ C1,
             OutT* __restrict__ C2, const int* __restrict__ flag)
{
  __shared__ __align__(16) bf16_t sA[2][128 * 40];  // 20 KB
  __shared__ __align__(16) bf16_t sB[2][128 * 32];  // 16 KB
  const int z = blockIdx.z;
  const void*   A = z == 0 ? A0 : (z == 1 ? A1 : A2);
  const bf16_t* W = Wb + (size_t)z * (1024 * 1024);
  OutT*         C = z == 0 ? C0 : (z == 1 ? C1 : C2);
  if (*flag) gemm_rs_core<true,  OutT>(A, W, C, sA, sB);
  else       gemm_rs_core<false, OutT>(A, W, C, sA, sB);
}

// ---------------------------------------------------------------------------
// gemm_o (output proj): C[8192,1024]f32 = A[8192,1024]bf16 @ W^T. Tile 64x128,
// BK=32, 4 waves (1x4: wave owns cols [w*32,w*32+32)), 4x2 mfma/wave.
// 1024 blocks -> 4 blocks/CU (was 2 at 128-tile). Same W g2l + swizzle path.
// ---------------------------------------------------------------------------
__global__ __launch_bounds__(256, 4)
void gemm_o(const bf16_t* __restrict__ A, const bf16_t* __restrict__ W,
            float* __restrict__ C)
{
  const int K = 1024;
  __shared__ __align__(16) bf16_t sA[2][64 * 40];   // 10 KB
  __shared__ __align__(16) bf16_t sB[2][128 * 32];  // 16 KB
  const int tid  = threadIdx.x;
  const int wave = tid >> 6;
  const int lane = tid & 63;
  int bm, bn;
  gemm_tile_map64(bm, bn);
  const int quad = lane >> 4, r16 = lane & 15;
  const int cW = (quad * 8) ^ ((r16 & 6) << 2);

  floatx4 acc[4][2];
  #pragma unroll
  for (int i = 0; i < 4; ++i)
    #pragma unroll
    for (int j = 0; j < 2; ++j) acc[i][j] = {0.f, 0.f, 0.f, 0.f};

  const int srow = tid >> 2;        // one row per thread (0..63)
  const int scol = (tid & 3) * 8;
  const size_t a0 = (size_t)(bm + srow) * K + scol;

  const int ch0 = wave * 2;
  const int r0  = lane >> 2;
  const int ce  = (lane & 3) * 8;
  const bf16_t* Wg0 = W + (size_t)(bn + ch0 * 16 + r0) * K + ce;
  const bf16_t* Wg1 = Wg0 + (size_t)16 * K;

  bf16x8 ba;
  auto stageA = [&](int k0) { ba = *(const bf16x8*)(A + a0 + k0); };

  stageA(0);
  g2l16(Wg0, &sB[0][ch0 * 512]);
  g2l16(Wg1, &sB[0][(ch0 + 1) * 512]);

  for (int t = 0; t < 32; ++t) {
    const int buf = t & 1;
    *(bf16x8*)&sA[buf][srow * 40 + scol] = ba;
    __syncthreads();  // drains W g2l(t); A writes visible
    if (t + 1 < 32) {
      const int k0 = (t + 1) * 32;
      g2l16(Wg0 + k0, &sB[buf ^ 1][ch0 * 512]);
      g2l16(Wg1 + k0, &sB[buf ^ 1][(ch0 + 1) * 512]);
      stageA(k0);
    }

    bf16x8 af[4], bv[2];
    #pragma unroll
    for (int mi = 0; mi < 4; ++mi)
      af[mi] = *(const bf16x8*)&sA[buf][(mi * 16 + r16) * 40 + quad * 8];
    #pragma unroll
    for (int ni = 0; ni < 2; ++ni)
      bv[ni] = *(const bf16x8*)&sB[buf][(wave * 32 + ni * 16 + r16) * 32 + cW];
    #pragma unroll
    for (int mi = 0; mi < 4; ++mi)
      #pragma unroll
      for (int ni = 0; ni < 2; ++ni)
        acc[mi][ni] = MFMA(af[mi], bv[ni], acc[mi][ni]);
  }

  #pragma unroll
  for (int mi = 0; mi < 4; ++mi)
    #pragma unroll
    for (int ni = 0; ni < 2; ++ni)
      #pragma unroll
      for (int r = 0; r < 4; ++r) {
        const int row = bm + mi * 16 + quad * 4 + r;
        const int col = bn + wave * 32 + ni * 16 + r16;
        C[(size_t)row * 1024 + col] = acc[mi][ni][r];
      }
}

// ---------------------------------------------------------------------------
// Causal MFMA flash attention over row-major [8192][1024] bf16 q/k/v, head =
// 64-col slice. Block = 256 threads (4 waves): one (bh, 64-row q-tile).
// Wave w owns q-rows [w*16, w*16+16). BKV = 64. Swapped QK^T: lane owns one
// q-row -> lane-local softmax (15 fmax + 2 shfl), T13 skip-rescale, bf16x4 P
// stores. XCD-grouped block map (K/V L2-hot), heavy tiles first. LDS 24 KB
// swizzled (idx = row*64 + (col^((row&7)<<3))). K/V reg-prefetch (T14).
// launch_bounds(256,4): VGPR 64, NO spill (R14's (256,6) -> 40 VGPR -> 1.1 GB
// scratch traffic, 3x slower. Never bound past the register footprint.)
// [R12 exact: 143 us]
// ---------------------------------------------------------------------------
__global__ __launch_bounds__(256, 4)
void flash_attn(bf16_t* qio, const bf16_t* __restrict__ kh,
                const bf16_t* __restrict__ vh)
{
  __shared__ __align__(16) bf16_t sK[64 * 64];    // [kv][d]  8 KB, swizzled
  __shared__ __align__(16) bf16_t sVt[64 * 64];   // [d][kv]  8 KB, swizzled
  __shared__ __align__(16) bf16_t sP[64 * 64];    // [q][kv]  8 KB, swizzled
  const int tid  = threadIdx.x;
  const int wave = tid >> 6;
  const int lane = tid & 63;
  const int quad = lane >> 4, r16 = lane & 15;

  const int f  = (int)(blockIdx.y * gridDim.x + blockIdx.x);
  const int xj = f & 7, sq = f >> 3;
  const int bh = xj + (sq >> 5) * 8;
  const int q0 = (31 - (sq & 31)) * 64;
  const int b = bh >> 4, h = bh & 15;
  const size_t hb = ((size_t)b * 2048) * 1024 + (size_t)h * 64;
  const int swl = (r16 & 7) << 3;  // swizzle XOR for r16-indexed rows

  bf16x8 qf[2];
  #pragma unroll
  for (int ks = 0; ks < 2; ++ks)
    qf[ks] = *(const bf16x8*)(qio + hb +
        (size_t)(q0 + wave * 16 + r16) * 1024 + ks * 32 + quad * 8);

  floatx4 o[4];
  #pragma unroll
  for (int nd = 0; nd < 4; ++nd) o[nd] = {0.f, 0.f, 0.f, 0.f};
  float mrow = NEG_BIG, lrow = 0.f;  // state for q-row (wave*16 + r16)

  const float sc = 0.125f * 1.44269504089f;  // 1/sqrt(64) * log2(e)
  const int kend = q0 + 64;
  const int qrow = q0 + wave * 16 + r16;

  bf16x8 kst[2], vst[2];
  #pragma unroll
  for (int j = 0; j < 2; ++j) {
    const int c = j * 256 + tid;
    kst[j] = *(const bf16x8*)(kh + hb + (size_t)(c >> 3) * 1024 + (c & 7) * 8);
    vst[j] = *(const bf16x8*)(vh + hb + (size_t)(c & 63) * 1024 + (c >> 6) * 8);
  }

  for (int kv0 = 0; kv0 < kend; kv0 += 64) {
    #pragma unroll
    for (int j = 0; j < 2; ++j) {
      const int c = j * 256 + tid;
      const int krow = c >> 3, kcol = (c & 7) * 8;
      *(bf16x8*)&sK[krow * 64 + (kcol ^ ((krow & 7) << 3))] = kst[j];
      const int vkv = c & 63, vd = (c >> 6) * 8;
      #pragma unroll
      for (int e = 0; e < 8; ++e)        // row = vd+e, (row&7)==e since vd%8==0
        sVt[(vd + e) * 64 + (vkv ^ (e << 3))] = vst[j][e];
    }
    __syncthreads();

    if (kv0 + 64 < kend) {
      #pragma unroll
      for (int j = 0; j < 2; ++j) {
        const int c = j * 256 + tid;
        kst[j] = *(const bf16x8*)(kh + hb + (size_t)(kv0 + 64 + (c >> 3)) * 1024 + (c & 7) * 8);
        vst[j] = *(const bf16x8*)(vh + hb + (size_t)(kv0 + 64 + (c & 63)) * 1024 + (c >> 6) * 8);
      }
    }

    floatx4 st[4];
    #pragma unroll
    for (int nk = 0; nk < 4; ++nk) st[nk] = {0.f, 0.f, 0.f, 0.f};
    #pragma unroll
    for (int ks = 0; ks < 2; ++ks) {
      bf16x8 bk[4];
      #pragma unroll
      for (int nk = 0; nk < 4; ++nk)
        bk[nk] = *(const bf16x8*)&sK[(nk * 16 + r16) * 64 + ((ks * 32 + quad * 8) ^ swl)];
      #pragma unroll
      for (int nk = 0; nk < 4; ++nk)
        st[nk] = MFMA(bk[nk], qf[ks], st[nk]);  // swapped operands
    }

    const bool domask = (kv0 + 63 > q0 + wave * 16);  // wave-uniform
    #pragma unroll
    for (int nk = 0; nk < 4; ++nk)
      #pragma unroll
      for (int r = 0; r < 4; ++r) {
        float t = st[nk][r] * sc;
        if (domask && (kv0 + nk * 16 + quad * 4 + r > qrow)) t = NEG_BIG;
        st[nk][r] = t;
      }

    float mx = fmaxf(fmaxf(st[0][0], st[0][1]), fmaxf(st[0][2], st[0][3]));
    #pragma unroll
    for (int nk = 1; nk < 4; ++nk)
      mx = fmaxf(mx, fmaxf(fmaxf(st[nk][0], st[nk][1]),
                           fmaxf(st[nk][2], st[nk][3])));
    mx = fmaxf(mx, __shfl_xor(mx, 16, 64));
    mx = fmaxf(mx, __shfl_xor(mx, 32, 64));

    if (!__all(mx <= mrow)) {            // T13: skip rescale if no max grew
      const float mnew  = fmaxf(mrow, mx);
      const float alpha = exp2f(mrow - mnew);
      mrow = mnew;
      lrow *= alpha;
      #pragma unroll
      for (int r = 0; r < 4; ++r) {
        const float ar = __shfl(alpha, quad * 4 + r, 64);
        #pragma unroll
        for (int nd = 0; nd < 4; ++nd) o[nd][r] *= ar;
      }
    }

    float ls = 0.f;
    #pragma unroll
    for (int nk = 0; nk < 4; ++nk) {
      bf16x4 pk;
      #pragma unroll
      for (int r = 0; r < 4; ++r) {
        const bf16_t pb = f2bf(exp2f(st[nk][r] - mrow));
        ls += (float)pb;  // denominator matches the bf16 P used in PV
        pk[r] = pb;
      }
      *(bf16x4*)&sP[(wave * 16 + r16) * 64 + ((nk * 16 + quad * 4) ^ swl)] = pk;
    }
    ls += __shfl_xor(ls, 16, 64);
    ls += __shfl_xor(ls, 32, 64);
    lrow += ls;
    __syncthreads();  // sP visible across lanes

    #pragma unroll
    for (int ks = 0; ks < 2; ++ks) {
      const int cb = (ks * 32 + quad * 8) ^ swl;
      const bf16x8 pa = *(const bf16x8*)&sP[(wave * 16 + r16) * 64 + cb];
      bf16x8 vb[4];
      #pragma unroll
      for (int nd = 0; nd < 4; ++nd)
        vb[nd] = *(const bf16x8*)&sVt[(nd * 16 + r16) * 64 + cb];
      #pragma unroll
      for (int nd = 0; nd < 4; ++nd)
        o[nd] = MFMA(pa, vb[nd], o[nd]);
    }
    __syncthreads();  // protect sK/sVt/sP for next iteration
  }

  #pragma unroll
  for (int r = 0; r < 4; ++r) {
    const float lr  = __shfl(lrow, quad * 4 + r, 64);
    const float inv = 1.f / lr;
    const int row = q0 + wave * 16 + quad * 4 + r;
    #pragma unroll
    for (int nd = 0; nd < 4; ++nd)
      qio[hb + (size_t)row * 1024 + nd * 16 + r16] = f2bf(o[nd][r] * inv);
  }
}

// ---------------------------------------------------------------------------
extern "C" void kernel_launch(void* const* d_in, const int* in_sizes, int n_in,
                              void* d_out, int out_size, void* d_ws, size_t ws_size,
                              hipStream_t stream) {
  (void)in_sizes; (void)n_in; (void)out_size; (void)ws_size;
  const size_t TSZ = (size_t)8192 * 1024;       // elems per [8192,1024] bf16
  int*    flag = (int*)d_ws;
  bf16_t* qws  = (bf16_t*)((char*)d_ws + 16);   // ws lo  16 MB
  bf16_t* kws  = qws + TSZ;                     // ws hi  16 MB (W_o slot later)
  bf16_t* vws  = (bf16_t*)d_out;                // d_out lo 16 MB (bf16 V)
  bf16_t* wsl  = (bf16_t*)d_out + TSZ;          // d_out hi: 3 x 2 MB W slots

  detect_dtype<<<1, 64, 0, stream>>>((const unsigned short*)d_in[3], flag);

  // convert+swizzle w_q, w_k, w_v into the three slots
  cvt_w_swz<<<dim3(512, 3), 256, 0, stream>>>(d_in[3], d_in[4], d_in[5], wsl, flag);

  // fused Q/K/V projections: one dispatch, 1536 blocks (3 blocks/CU)
  gemm_rs<bf16_t><<<dim3(8, 64, 3), 256, 0, stream>>>(
      d_in[0], d_in[1], d_in[2], wsl, qws, kws, vws, flag);

  flash_attn<<<dim3(64, 32), 256, 0, stream>>>(qws, kws, vws);

  // K dead -> its ws region holds converted+swizzled w_o
  cvt_w_swz<<<dim3(512, 1), 256, 0, stream>>>(d_in[6], d_in[6], d_in[6], kws, flag);

  // output projection: 64x128 tile, 1024 blocks (4 blocks/CU; was 2)
  gemm_o<<<dim3(8, 128), 256, 0, stream>>>(qws, kws, (float*)d_out);
}